// Round 2
// baseline (1223.299 us; speedup 1.0000x reference)
//
#include <hip/hip_runtime.h>
#include <hip/hip_bf16.h>
#include <math.h>

#define HNUM 16
#define LOGIT_MAX 4.605170185988091f

// ---------------- GEMM NT: C[M,N] = A[M,K] * B[N,K]^T (+bias) ----------------
// Tile 128x128, BK=16, 256 threads, 8x8 per thread. M%128==0, N%128==0, K%16==0.
template<bool BIAS>
__global__ __launch_bounds__(256)
void gemm_nt(const float* __restrict__ A, const float* __restrict__ Bm,
             const float* __restrict__ bias, float* __restrict__ C,
             int M, int N, int K) {
    __shared__ float as[16][132];
    __shared__ float bs[16][132];
    const int t = threadIdx.x;
    const int row0 = blockIdx.y * 128;
    const int col0 = blockIdx.x * 128;
    const int tx = t & 15, ty = t >> 4;
    const int k4 = (t & 3) << 2;   // 0,4,8,12
    const int rr = t >> 2;         // 0..63

    float acc[8][8];
    #pragma unroll
    for (int i = 0; i < 8; ++i)
        #pragma unroll
        for (int j = 0; j < 8; ++j) acc[i][j] = 0.f;

    const float* Ap = A + (size_t)(row0 + rr) * K + k4;
    const float* Bp = Bm + (size_t)(col0 + rr) * K + k4;

    for (int k0 = 0; k0 < K; k0 += 16) {
        float4 a0 = *(const float4*)(Ap + k0);
        float4 a1 = *(const float4*)(Ap + (size_t)64 * K + k0);
        float4 b0 = *(const float4*)(Bp + k0);
        float4 b1 = *(const float4*)(Bp + (size_t)64 * K + k0);
        __syncthreads();
        as[k4+0][rr] = a0.x; as[k4+1][rr] = a0.y; as[k4+2][rr] = a0.z; as[k4+3][rr] = a0.w;
        as[k4+0][rr+64] = a1.x; as[k4+1][rr+64] = a1.y; as[k4+2][rr+64] = a1.z; as[k4+3][rr+64] = a1.w;
        bs[k4+0][rr] = b0.x; bs[k4+1][rr] = b0.y; bs[k4+2][rr] = b0.z; bs[k4+3][rr] = b0.w;
        bs[k4+0][rr+64] = b1.x; bs[k4+1][rr+64] = b1.y; bs[k4+2][rr+64] = b1.z; bs[k4+3][rr+64] = b1.w;
        __syncthreads();
        #pragma unroll
        for (int kk = 0; kk < 16; ++kk) {
            float av[8], bv[8];
            float4 x0 = *(const float4*)&as[kk][ty*8];
            float4 x1 = *(const float4*)&as[kk][ty*8+4];
            av[0]=x0.x; av[1]=x0.y; av[2]=x0.z; av[3]=x0.w;
            av[4]=x1.x; av[5]=x1.y; av[6]=x1.z; av[7]=x1.w;
            #pragma unroll
            for (int c = 0; c < 8; ++c) bv[c] = bs[kk][tx + 16*c];
            #pragma unroll
            for (int i = 0; i < 8; ++i)
                #pragma unroll
                for (int c = 0; c < 8; ++c)
                    acc[i][c] = fmaf(av[i], bv[c], acc[i][c]);
        }
    }
    #pragma unroll
    for (int i = 0; i < 8; ++i) {
        const int row = row0 + ty*8 + i;
        #pragma unroll
        for (int c = 0; c < 8; ++c) {
            const int col = col0 + tx + 16*c;
            float v = acc[i][c];
            if (BIAS) v += bias[col];
            C[(size_t)row * N + col] = v;
        }
    }
}

// -------- L2-normalize 64-element head segments in place; optional q scale ----
__global__ __launch_bounds__(256)
void l2norm_seg(float* __restrict__ p, int row_stride, int n_rows,
                const float* __restrict__ logit_scale) {
    const int seg = blockIdx.x * 4 + (threadIdx.x >> 6);
    const int lane = threadIdx.x & 63;
    if (seg >= n_rows * HNUM) return;
    const int row = seg >> 4, h = seg & 15;
    float* q = p + (size_t)row * row_stride + h * 64;
    float x = q[lane];
    float ss = x * x;
    #pragma unroll
    for (int off = 32; off; off >>= 1) ss += __shfl_xor(ss, off);
    float inv = 1.0f / fmaxf(sqrtf(ss), 1e-12f);
    if (logit_scale) inv *= __expf(fminf(logit_scale[h], LOGIT_MAX));
    q[lane] = x * inv;
}

// ---------------- Flash attention, f32, QBLK=32, KBLK=64 ----------------
// qn: [B*1024, 1024] normalized*scale; kvp: [B*2048, 2048] (k normalized, v raw)
// alibi: [B,16,1024,2048]; mask: [B,2048] int32; xout: [B*1024, 1024] (b,n,h,d)
__global__ __launch_bounds__(256)
void attn_f32(const float* __restrict__ qn, const float* __restrict__ kvp,
              const float* __restrict__ alibi, const int* __restrict__ mask,
              float* __restrict__ xout) {
    __shared__ float q_s[32][65];
    __shared__ float ks[64][65];
    __shared__ float vs[64][65];
    __shared__ float ps[32][65];

    const int t = threadIdx.x;
    const int bh = blockIdx.y;
    const int b = bh >> 4, h = bh & 15;
    const int n0 = blockIdx.x * 32;
    const int qg = t >> 4;       // 0..15 -> q rows 2qg, 2qg+1
    const int mg = t & 15;       // 0..15 -> m (or d) cols 4mg..4mg+3

    {   // load q tile: 32x64
        const int rr = t >> 3;          // 0..31
        const int c8 = (t & 7) << 3;    // 0..56
        const float* src = qn + (size_t)(b * 1024 + n0 + rr) * 1024 + h * 64 + c8;
        float4 v0 = *(const float4*)src;
        float4 v1 = *(const float4*)(src + 4);
        q_s[rr][c8+0]=v0.x; q_s[rr][c8+1]=v0.y; q_s[rr][c8+2]=v0.z; q_s[rr][c8+3]=v0.w;
        q_s[rr][c8+4]=v1.x; q_s[rr][c8+5]=v1.y; q_s[rr][c8+6]=v1.z; q_s[rr][c8+7]=v1.w;
    }

    float mrow[2] = {-1e30f, -1e30f};
    float lrow[2] = {0.f, 0.f};
    float o[2][4] = {{0,0,0,0},{0,0,0,0}};

    const int srr = t >> 2;         // 0..63
    const int sc  = (t & 3) << 4;   // 0,16,32,48
    const float* kbase = kvp + (size_t)(b * 2048) * 2048 + h * 64;
    const float* albase = alibi + ((size_t)bh * 1024 + n0) * 2048;
    const int* mbase = mask + b * 2048;

    for (int m0 = 0; m0 < 2048; m0 += 64) {
        __syncthreads();
        {   // stage K,V tile 64x64 each
            const float* kp = kbase + (size_t)(m0 + srr) * 2048 + sc;
            const float* vp = kp + 1024;
            #pragma unroll
            for (int j = 0; j < 4; ++j) {
                float4 k4 = *(const float4*)(kp + 4*j);
                float4 v4 = *(const float4*)(vp + 4*j);
                ks[srr][sc+4*j+0]=k4.x; ks[srr][sc+4*j+1]=k4.y; ks[srr][sc+4*j+2]=k4.z; ks[srr][sc+4*j+3]=k4.w;
                vs[srr][sc+4*j+0]=v4.x; vs[srr][sc+4*j+1]=v4.y; vs[srr][sc+4*j+2]=v4.z; vs[srr][sc+4*j+3]=v4.w;
            }
        }
        __syncthreads();
        // scores s[2][4]
        float s[2][4] = {{0,0,0,0},{0,0,0,0}};
        #pragma unroll 8
        for (int dd = 0; dd < 64; ++dd) {
            float qa = q_s[2*qg+0][dd];
            float qb = q_s[2*qg+1][dd];
            #pragma unroll
            for (int c = 0; c < 4; ++c) {
                float kv = ks[4*mg + c][dd];
                s[0][c] = fmaf(qa, kv, s[0][c]);
                s[1][c] = fmaf(qb, kv, s[1][c]);
            }
        }
        // alibi + padding mask (mask is int32 per harness integer convention)
        const int4 mk = *(const int4*)(mbase + m0 + 4*mg);
        const int mkv[4] = {mk.x, mk.y, mk.z, mk.w};
        #pragma unroll
        for (int r = 0; r < 2; ++r) {
            const float4 al = *(const float4*)(albase + (size_t)(2*qg + r) * 2048 + m0 + 4*mg);
            const float alv[4] = {al.x, al.y, al.z, al.w};
            #pragma unroll
            for (int c = 0; c < 4; ++c)
                s[r][c] = mkv[c] ? -1e30f : (s[r][c] + alv[c]);
        }
        // online softmax
        #pragma unroll
        for (int r = 0; r < 2; ++r) {
            float mx = fmaxf(fmaxf(s[r][0], s[r][1]), fmaxf(s[r][2], s[r][3]));
            mx = fmaxf(mx, __shfl_xor(mx, 1));
            mx = fmaxf(mx, __shfl_xor(mx, 2));
            mx = fmaxf(mx, __shfl_xor(mx, 4));
            mx = fmaxf(mx, __shfl_xor(mx, 8));
            const float mnew = fmaxf(mrow[r], mx);
            const float f = __expf(mrow[r] - mnew);
            float p[4], sum = 0.f;
            #pragma unroll
            for (int c = 0; c < 4; ++c) { p[c] = __expf(s[r][c] - mnew); sum += p[c]; }
            sum += __shfl_xor(sum, 1); sum += __shfl_xor(sum, 2);
            sum += __shfl_xor(sum, 4); sum += __shfl_xor(sum, 8);
            lrow[r] = lrow[r] * f + sum;
            mrow[r] = mnew;
            #pragma unroll
            for (int c = 0; c < 4; ++c) { o[r][c] *= f; ps[2*qg+r][4*mg+c] = p[c]; }
        }
        __syncthreads();
        // PV: o[r][c] += sum_m p[2qg+r][m] * v[m][4mg+c]
        #pragma unroll 8
        for (int m = 0; m < 64; ++m) {
            float pa = ps[2*qg+0][m];
            float pb = ps[2*qg+1][m];
            #pragma unroll
            for (int c = 0; c < 4; ++c) {
                float vv = vs[m][4*mg + c];
                o[0][c] = fmaf(pa, vv, o[0][c]);
                o[1][c] = fmaf(pb, vv, o[1][c]);
            }
        }
    }
    #pragma unroll
    for (int r = 0; r < 2; ++r) {
        const float inv = 1.0f / lrow[r];
        float4 w = make_float4(o[r][0]*inv, o[r][1]*inv, o[r][2]*inv, o[r][3]*inv);
        *(float4*)(xout + (size_t)(b * 1024 + n0 + 2*qg + r) * 1024 + h * 64 + 4*mg) = w;
    }
}

extern "C" void kernel_launch(void* const* d_in, const int* in_sizes, int n_in,
                              void* d_out, int out_size, void* d_ws, size_t ws_size,
                              hipStream_t stream) {
    const float* q   = (const float*)d_in[0];   // [2,1024,1024]
    const float* kv  = (const float*)d_in[1];   // [2,2048,1024]
    const int* pmask = (const int*)d_in[2];     // [2,2048] bool -> int32
    const float* alibi = (const float*)d_in[3]; // [2,16,1024,2048]
    const float* Wq  = (const float*)d_in[4];   // [1024,1024]
    const float* Wkv = (const float*)d_in[5];   // [2048,1024]
    const float* Wo  = (const float*)d_in[6];   // [1024,1024]
    const float* bo  = (const float*)d_in[7];   // [1024]
    const float* ls  = (const float*)d_in[8];   // [16,1,1]
    float* out = (float*)d_out;                 // [2,1024,1024]

    float* qh  = (float*)d_ws;                        // 2M floats
    float* kvp = qh + (size_t)2*1024*1024;            // 8M floats
    float* xb  = kvp + (size_t)8*1024*1024;           // 2M floats

    // 1) qh = q @ Wq^T   [2048,1024]
    gemm_nt<false><<<dim3(1024/128, 2048/128), 256, 0, stream>>>(q, Wq, nullptr, qh, 2048, 1024, 1024);
    // 2) kvp = kv @ Wkv^T  [4096,2048]
    gemm_nt<false><<<dim3(2048/128, 4096/128), 256, 0, stream>>>(kv, Wkv, nullptr, kvp, 4096, 2048, 1024);
    // 3) normalize q heads (fold in clamped logit scale)
    l2norm_seg<<<dim3(2048*16/4), 256, 0, stream>>>(qh, 1024, 2048, ls);
    // 4) normalize k heads
    l2norm_seg<<<dim3(4096*16/4), 256, 0, stream>>>(kvp, 2048, 4096, nullptr);
    // 5) attention
    attn_f32<<<dim3(1024/32, 2*16), 256, 0, stream>>>(qh, kvp, alibi, pmask, xb);
    // 6) out = xb @ Wo^T + bo
    gemm_nt<true><<<dim3(1024/128, 2048/128), 256, 0, stream>>>(xb, Wo, bo, out, 2048, 1024, 1024);
}

// Round 3
// 195.844 us; speedup vs baseline: 6.2463x; 6.2463x over previous
//
#include <hip/hip_runtime.h>
#include <hip/hip_bf16.h>
#include <math.h>

typedef unsigned short u16;
typedef unsigned int u32;
using f32x4 = __attribute__((ext_vector_type(4))) float;
using short8 = __attribute__((ext_vector_type(8))) short;

#define LOGIT_MAX 4.605170185988091f
#define MFMA16(a,b,c) __builtin_amdgcn_mfma_f32_16x16x32_bf16((a),(b),(c),0,0,0)
// LDS XOR swizzles for 128B rows (m214: byte ^= ((row&7)<<4))
#define SWZK(r) ((((r)&7))<<4)
#define SWZV(r) (((((r)^((r)>>3))&7))<<4)

__device__ __forceinline__ u16 f2bf(float f) {
  u32 u = __float_as_uint(f);
  return (u16)((u + 0x7FFFu + ((u >> 16) & 1u)) >> 16);  // RNE
}
__device__ __forceinline__ float bf2f(u16 s) {
  return __uint_as_float(((u32)s) << 16);
}
__device__ __forceinline__ void gload16(const void* g, void* l) {
  __builtin_amdgcn_global_load_lds(
      (const __attribute__((address_space(1))) u32*)g,
      (__attribute__((address_space(3))) u32*)l, 16, 0, 0);
}

// ---------------- f32 -> bf16 cast, 8 elems/thread ----------------
__global__ __launch_bounds__(256) void cast_bf16(const float* __restrict__ s,
                                                 u16* __restrict__ d, int n) {
  int i = (blockIdx.x * 256 + threadIdx.x) * 8;
  if (i >= n) return;
  float4 a = *(const float4*)(s + i);
  float4 b = *(const float4*)(s + i + 4);
  short8 v;
  v[0] = (short)f2bf(a.x); v[1] = (short)f2bf(a.y);
  v[2] = (short)f2bf(a.z); v[3] = (short)f2bf(a.w);
  v[4] = (short)f2bf(b.x); v[5] = (short)f2bf(b.y);
  v[6] = (short)f2bf(b.z); v[7] = (short)f2bf(b.w);
  *(short8*)(d + i) = v;
}

// ------------- GEMM NT bf16: C[M,N] = A[M,K] * B[N,K]^T (m97 structure) -------------
template<bool BIAS, bool BF16OUT>
__global__ __launch_bounds__(256) void gemm_bf16(
    const u16* __restrict__ A, const u16* __restrict__ B,
    const float* __restrict__ bias, void* __restrict__ Cv,
    int M, int N, int K)
{
  __shared__ __align__(16) u16 a_s[128 * 32];
  __shared__ __align__(16) u16 b_s[128 * 32];
  const int t = threadIdx.x, w = t >> 6, l = t & 63, lo = l & 15, g = (l >> 4) & 3;
  const int row0 = blockIdx.y * 128, col0 = blockIdx.x * 128;
  const int wr = (w >> 1) * 64, wc = (w & 1) * 64;
  f32x4 acc[4][4];
  #pragma unroll
  for (int i = 0; i < 4; ++i)
    #pragma unroll
    for (int j = 0; j < 4; ++j) { acc[i][j][0]=0.f; acc[i][j][1]=0.f; acc[i][j][2]=0.f; acc[i][j][3]=0.f; }

  const int sr = l >> 2, sc = (l & 3) * 8;
  const u16* Ag = A + (size_t)(row0 + w * 32 + sr) * K + sc;
  const u16* Bg = B + (size_t)(col0 + w * 32 + sr) * K + sc;
  u16* adst = a_s + w * 1024;
  u16* bdst = b_s + w * 1024;

  for (int k0 = 0; k0 < K; k0 += 32) {
    __syncthreads();
    gload16(Ag + k0, adst);
    gload16(Ag + (size_t)16 * K + k0, adst + 512);
    gload16(Bg + k0, bdst);
    gload16(Bg + (size_t)16 * K + k0, bdst + 512);
    __syncthreads();
    short8 af[4], bfr[4];
    #pragma unroll
    for (int mt = 0; mt < 4; ++mt) af[mt] = *(const short8*)&a_s[(wr + mt * 16 + lo) * 32 + g * 8];
    #pragma unroll
    for (int nt = 0; nt < 4; ++nt) bfr[nt] = *(const short8*)&b_s[(wc + nt * 16 + lo) * 32 + g * 8];
    #pragma unroll
    for (int mt = 0; mt < 4; ++mt)
      #pragma unroll
      for (int nt = 0; nt < 4; ++nt)
        acc[mt][nt] = MFMA16(af[mt], bfr[nt], acc[mt][nt]);
  }
  #pragma unroll
  for (int mt = 0; mt < 4; ++mt) {
    const int rrow = row0 + wr + mt * 16 + g * 4;
    #pragma unroll
    for (int nt = 0; nt < 4; ++nt) {
      const int ccol = col0 + wc + nt * 16 + lo;
      const float bv = BIAS ? bias[ccol] : 0.f;
      #pragma unroll
      for (int r = 0; r < 4; ++r) {
        const float v = acc[mt][nt][r] + bv;
        if (BF16OUT) ((u16*)Cv)[(size_t)(rrow + r) * N + ccol] = f2bf(v);
        else         ((float*)Cv)[(size_t)(rrow + r) * N + ccol] = v;
      }
    }
  }
}

// -------- in-place L2-normalize 64-elem head segments of bf16 rows --------
template<bool SCALE>
__global__ __launch_bounds__(256) void norm_heads(u16* __restrict__ p, int stride,
                                                  const float* __restrict__ ls) {
  const int t = threadIdx.x, h = t >> 4, ln = t & 15;
  u16* q = p + (size_t)blockIdx.x * stride + h * 64 + ln * 4;
  ushort4 uv = *(const ushort4*)q;
  float x0 = bf2f(uv.x), x1 = bf2f(uv.y), x2 = bf2f(uv.z), x3 = bf2f(uv.w);
  float ss = x0 * x0 + x1 * x1 + x2 * x2 + x3 * x3;
  ss += __shfl_xor(ss, 1); ss += __shfl_xor(ss, 2);
  ss += __shfl_xor(ss, 4); ss += __shfl_xor(ss, 8);
  float inv = 1.f / fmaxf(sqrtf(ss), 1e-12f);
  if (SCALE) inv *= __expf(fminf(ls[h], LOGIT_MAX));
  ushort4 ov;
  ov.x = f2bf(x0 * inv); ov.y = f2bf(x1 * inv);
  ov.z = f2bf(x2 * inv); ov.w = f2bf(x3 * inv);
  *(ushort4*)q = ov;
}

// ---------------- Flash attention, bf16 MFMA, QBLK=64, KVBLK=64, 4 waves ----------------
// qn: [B*1024][1024] bf16 (normalized*scale); kvp: [B*2048][2048] bf16 (k normed | v)
// swapped QK^T: S^T tile = mfma(K_frag, Q_frag) -> lane holds S[n=lo][m=m0+mt*16+4g+r]
__global__ __launch_bounds__(256) void attn_mfma(
    const u16* __restrict__ qn, const u16* __restrict__ kvp,
    const float* __restrict__ alibi, const int* __restrict__ mask,
    u16* __restrict__ xb)
{
  __shared__ __align__(16) u16 k_s[64 * 64];
  __shared__ __align__(16) u16 vT_s[64 * 64];
  __shared__ __align__(16) u16 p_s[4][16 * 64];
  const int t = threadIdx.x, w = t >> 6, l = t & 63, lo = l & 15, g = (l >> 4) & 3;
  const int bid = blockIdx.x;
  const int bh = bid & 31, b = bh >> 4, h = bh & 15;   // bid%8 == bh%8 -> same-(b,h) blocks share an XCD
  const int n0 = (bid >> 5) * 64;

  const u16* qrow = qn + (size_t)(b * 1024 + n0 + w * 16 + lo) * 1024 + h * 64;
  const short8 qf0 = *(const short8*)(qrow + g * 8);
  const short8 qf1 = *(const short8*)(qrow + 32 + g * 8);

  const u16* kbase = kvp + (size_t)(b * 2048) * 2048 + h * 64;
  const u16* vbase = kbase + 1024;
  const float* albase = alibi + ((size_t)(bh * 1024 + n0 + w * 16 + lo)) * 2048;
  const int* mbase = mask + b * 2048;

  const int kr0 = w * 16 + (l >> 3);
  const int kcolb = (l & 7) * 16;
  const int vdq = (t & 7) * 8;        // d0 of this thread's V micro-tile
  const int vmp = (t >> 3) * 2;       // m (even) of this thread's V micro-tile

  float mrow = -1e30f, lrow = 0.f;
  f32x4 oa[4];
  #pragma unroll
  for (int d = 0; d < 4; ++d) { oa[d][0]=0.f; oa[d][1]=0.f; oa[d][2]=0.f; oa[d][3]=0.f; }

  char* ksB = (char*)k_s;
  char* pwB = (char*)p_s[w];

  for (int m0 = 0; m0 < 2048; m0 += 64) {
    // prefetch alibi + mask (global, independent of LDS) for overlap
    float4 al[4]; int4 mk[4];
    #pragma unroll
    for (int mt = 0; mt < 4; ++mt) {
      al[mt] = *(const float4*)(albase + m0 + mt * 16 + g * 4);
      mk[mt] = *(const int4*)(mbase + m0 + mt * 16 + g * 4);
    }
    __syncthreads();   // prior tile fully consumed
    // stage K via global_load_lds with pre-swizzled global source (rule #21)
    {
      int r = kr0;
      gload16((const char*)kbase + (size_t)(m0 + r) * 4096 + (kcolb ^ SWZK(r)), ksB + w * 2048);
      r = kr0 + 8;
      gload16((const char*)kbase + (size_t)(m0 + r) * 4096 + (kcolb ^ SWZK(r)), ksB + w * 2048 + 1024);
    }
    // stage V transposed (reg-staged, packed b32, swizzled)
    {
      const u16* v0p = vbase + (size_t)(m0 + vmp) * 2048 + vdq;
      short8 va = *(const short8*)v0p;
      short8 vb = *(const short8*)(v0p + 2048);
      #pragma unroll
      for (int j = 0; j < 8; ++j) {
        u32 pk = (u32)(u16)va[j] | ((u32)(u16)vb[j] << 16);
        int r = vdq + j;
        *(u32*)((char*)vT_s + r * 128 + ((vmp * 2) ^ SWZV(r))) = pk;
      }
    }
    __syncthreads();

    // QK^T (swapped): st[mt] holds S[n=lo][m = m0 + mt*16 + 4g + r]
    f32x4 st[4];
    #pragma unroll
    for (int mt = 0; mt < 4; ++mt) {
      const int r = mt * 16 + lo;
      const char* krow = ksB + r * 128;
      short8 ka0 = *(const short8*)(krow + ((g * 16) ^ SWZK(r)));
      short8 ka1 = *(const short8*)(krow + ((64 + g * 16) ^ SWZK(r)));
      f32x4 z; z[0]=0.f; z[1]=0.f; z[2]=0.f; z[3]=0.f;
      st[mt] = MFMA16(ka0, qf0, z);
      st[mt] = MFMA16(ka1, qf1, st[mt]);
    }
    // alibi + padding mask
    float p[16];
    float pmax = -1e30f;
    #pragma unroll
    for (int mt = 0; mt < 4; ++mt) {
      const int   mm[4] = {mk[mt].x, mk[mt].y, mk[mt].z, mk[mt].w};
      const float aa[4] = {al[mt].x, al[mt].y, al[mt].z, al[mt].w};
      #pragma unroll
      for (int r = 0; r < 4; ++r) {
        const float v = mm[r] ? -1e30f : (st[mt][r] + aa[r]);
        p[mt * 4 + r] = v;
        pmax = fmaxf(pmax, v);
      }
    }
    pmax = fmaxf(pmax, __shfl_xor(pmax, 16));
    pmax = fmaxf(pmax, __shfl_xor(pmax, 32));
    const float mnew = fmaxf(mrow, pmax);
    const float f = __expf(mrow - mnew);
    float sum = 0.f;
    #pragma unroll
    for (int i = 0; i < 16; ++i) { p[i] = __expf(p[i] - mnew); sum += p[i]; }
    sum += __shfl_xor(sum, 16);
    sum += __shfl_xor(sum, 32);
    lrow = lrow * f + sum;
    mrow = mnew;
    // write P (bf16) to per-wave LDS, swizzled; read back as PV A-frags
    #pragma unroll
    for (int mt = 0; mt < 4; ++mt) {
      uint2 u;
      u.x = (u32)f2bf(p[mt * 4 + 0]) | ((u32)f2bf(p[mt * 4 + 1]) << 16);
      u.y = (u32)f2bf(p[mt * 4 + 2]) | ((u32)f2bf(p[mt * 4 + 3]) << 16);
      *(uint2*)(pwB + lo * 128 + ((mt * 32 + g * 8) ^ SWZK(lo))) = u;
    }
    asm volatile("" ::: "memory");  // order P write before P read (same wave, DS in-order)
    // rescale O accumulators (O row n = 4g+r; f lives at lane n)
    const float f0 = __shfl(f, 4 * g + 0), f1 = __shfl(f, 4 * g + 1);
    const float f2v = __shfl(f, 4 * g + 2), f3 = __shfl(f, 4 * g + 3);
    f32x4 fv; fv[0] = f0; fv[1] = f1; fv[2] = f2v; fv[3] = f3;
    #pragma unroll
    for (int d = 0; d < 4; ++d) oa[d] *= fv;
    // PV: O[n][dv] += P·V
    #pragma unroll
    for (int kt = 0; kt < 2; ++kt) {
      short8 pa = *(const short8*)(pwB + lo * 128 + ((kt * 64 + g * 16) ^ SWZK(lo)));
      #pragma unroll
      for (int d = 0; d < 4; ++d) {
        const int r = d * 16 + lo;
        short8 vf = *(const short8*)((const char*)vT_s + r * 128 + ((kt * 64 + g * 16) ^ SWZV(r)));
        oa[d] = MFMA16(pa, vf, oa[d]);
      }
    }
  }
  // epilogue: divide by row sums and store bf16
  const float l0 = __shfl(lrow, 4 * g + 0), l1 = __shfl(lrow, 4 * g + 1);
  const float l2 = __shfl(lrow, 4 * g + 2), l3 = __shfl(lrow, 4 * g + 3);
  const float iv[4] = {1.f / l0, 1.f / l1, 1.f / l2, 1.f / l3};
  u16* xrow = xb + (size_t)(b * 1024 + n0 + w * 16) * 1024 + h * 64;
  #pragma unroll
  for (int d = 0; d < 4; ++d)
    #pragma unroll
    for (int r = 0; r < 4; ++r)
      xrow[(size_t)(4 * g + r) * 1024 + d * 16 + lo] = f2bf(oa[d][r] * iv[r]);
}

extern "C" void kernel_launch(void* const* d_in, const int* in_sizes, int n_in,
                              void* d_out, int out_size, void* d_ws, size_t ws_size,
                              hipStream_t stream) {
  const float* q     = (const float*)d_in[0];   // [2,1024,1024]
  const float* kv    = (const float*)d_in[1];   // [2,2048,1024]
  const int*   pmask = (const int*)d_in[2];     // [2,2048] bool->int32
  const float* alibi = (const float*)d_in[3];   // [2,16,1024,2048]
  const float* Wq    = (const float*)d_in[4];   // [1024,1024]
  const float* Wkv   = (const float*)d_in[5];   // [2048,1024]
  const float* Wo    = (const float*)d_in[6];   // [1024,1024]
  const float* bo    = (const float*)d_in[7];   // [1024]
  const float* ls    = (const float*)d_in[8];   // [16]
  float* out = (float*)d_out;                   // [2,1024,1024]

  u16* ws = (u16*)d_ws;                          // 44 MB total
  u16* q_bf   = ws;
  u16* kv_bf  = ws + (size_t)2  * 1024 * 1024;
  u16* Wq_bf  = ws + (size_t)6  * 1024 * 1024;
  u16* Wkv_bf = ws + (size_t)7  * 1024 * 1024;
  u16* Wo_bf  = ws + (size_t)9  * 1024 * 1024;
  u16* qh_bf  = ws + (size_t)10 * 1024 * 1024;  // [2048][1024]
  u16* kvp_bf = ws + (size_t)12 * 1024 * 1024;  // [4096][2048]
  u16* xb     = ws + (size_t)20 * 1024 * 1024;  // [2048][1024]

  cast_bf16<<<1024, 256, 0, stream>>>(q,   q_bf,   2 * 1024 * 1024);
  cast_bf16<<<2048, 256, 0, stream>>>(kv,  kv_bf,  4 * 1024 * 1024);
  cast_bf16<<<512,  256, 0, stream>>>(Wq,  Wq_bf,  1024 * 1024);
  cast_bf16<<<1024, 256, 0, stream>>>(Wkv, Wkv_bf, 2 * 1024 * 1024);
  cast_bf16<<<512,  256, 0, stream>>>(Wo,  Wo_bf,  1024 * 1024);

  gemm_bf16<false, true><<<dim3(8, 16),  256, 0, stream>>>(q_bf,  Wq_bf,  nullptr, qh_bf,  2048, 1024, 1024);
  gemm_bf16<false, true><<<dim3(16, 32), 256, 0, stream>>>(kv_bf, Wkv_bf, nullptr, kvp_bf, 4096, 2048, 1024);

  norm_heads<true ><<<2048, 256, 0, stream>>>(qh_bf,  1024, ls);
  norm_heads<false><<<4096, 256, 0, stream>>>(kvp_bf, 2048, nullptr);

  attn_mfma<<<512, 256, 0, stream>>>(qh_bf, kvp_bf, alibi, pmask, xb);

  gemm_bf16<true, false><<<dim3(8, 16), 256, 0, stream>>>(xb, Wo_bf, bo, out, 2048, 1024, 1024);
}

// Round 4
// 177.460 us; speedup vs baseline: 6.8934x; 1.1036x over previous
//
#include <hip/hip_runtime.h>
#include <hip/hip_bf16.h>
#include <math.h>

typedef unsigned short u16;
typedef unsigned int u32;
using f32x4 = __attribute__((ext_vector_type(4))) float;
using short8 = __attribute__((ext_vector_type(8))) short;

#define LOGIT_MAX 4.605170185988091f
#define MFMA16(a,b,c) __builtin_amdgcn_mfma_f32_16x16x32_bf16((a),(b),(c),0,0,0)
// LDS XOR swizzles for 128B rows (m214: byte ^= ((row&7)<<4))
#define SWZK(r) ((((r)&7))<<4)
#define SWZV(r) (((((r)^((r)>>3))&7))<<4)

__device__ __forceinline__ u16 f2bf(float f) {
  u32 u = __float_as_uint(f);
  return (u16)((u + 0x7FFFu + ((u >> 16) & 1u)) >> 16);  // RNE
}
__device__ __forceinline__ float bf2f(u16 s) {
  return __uint_as_float(((u32)s) << 16);
}
__device__ __forceinline__ void gload16(const void* g, void* l) {
  __builtin_amdgcn_global_load_lds(
      (const __attribute__((address_space(1))) u32*)g,
      (__attribute__((address_space(3))) u32*)l, 16, 0, 0);
}

// ------- fused f32->bf16 casts (5 regions) + padding-mask->bitmask -------
__global__ __launch_bounds__(256) void cast_all(
    const float* __restrict__ q, const float* __restrict__ kv,
    const float* __restrict__ Wq, const float* __restrict__ Wkv,
    const float* __restrict__ Wo, const int* __restrict__ pm,
    u16* __restrict__ qb, u16* __restrict__ kvb, u16* __restrict__ wqb,
    u16* __restrict__ wkvb, u16* __restrict__ wob, u32* __restrict__ mbits) {
  const int bid = blockIdx.x, t = threadIdx.x;
  if (bid == 5120) {  // mask -> bits: [2][2048] int -> [2][64] u32
    if (t < 128) {
      u32 bits = 0;
      const int* mp = pm + (t >> 6) * 2048 + (t & 63) * 32;
      #pragma unroll
      for (int j = 0; j < 32; ++j) bits |= (mp[j] ? 1u : 0u) << j;
      mbits[t] = bits;
    }
    return;
  }
  const float* s; u16* d; int base;
  if (bid < 1024)      { s = q;   d = qb;   base = bid; }
  else if (bid < 3072) { s = kv;  d = kvb;  base = bid - 1024; }
  else if (bid < 3584) { s = Wq;  d = wqb;  base = bid - 3072; }
  else if (bid < 4608) { s = Wkv; d = wkvb; base = bid - 3584; }
  else                 { s = Wo;  d = wob;  base = bid - 4608; }
  const size_t i = ((size_t)base * 256 + t) * 8;
  float4 a = *(const float4*)(s + i);
  float4 b = *(const float4*)(s + i + 4);
  short8 v;
  v[0] = (short)f2bf(a.x); v[1] = (short)f2bf(a.y);
  v[2] = (short)f2bf(a.z); v[3] = (short)f2bf(a.w);
  v[4] = (short)f2bf(b.x); v[5] = (short)f2bf(b.y);
  v[6] = (short)f2bf(b.z); v[7] = (short)f2bf(b.w);
  *(short8*)(d + i) = v;
}

// ------------- GEMM NT bf16: C[M,N] = A[M,K] * B[N,K]^T -------------
// BN=128: 4 waves in 2x2, 64x64 each. BN=64: 4 waves stacked, 32x64 each.
template<int BN, bool BIAS, bool BF16OUT>
__global__ __launch_bounds__(256) void gemm_bf16(
    const u16* __restrict__ A, const u16* __restrict__ B,
    const float* __restrict__ bias, void* __restrict__ Cv,
    int M, int N, int K)
{
  constexpr int MT = (BN == 128) ? 4 : 2;
  __shared__ __align__(16) u16 a_s[128 * 32];
  __shared__ __align__(16) u16 b_s[BN * 32];
  const int t = threadIdx.x, w = t >> 6, l = t & 63, lo = l & 15, g = (l >> 4) & 3;
  const int row0 = blockIdx.y * 128, col0 = blockIdx.x * BN;
  const int wr = (BN == 128) ? ((w >> 1) * 64) : (w * 32);
  const int wc = (BN == 128) ? ((w & 1) * 64) : 0;
  f32x4 acc[MT][4];
  #pragma unroll
  for (int i = 0; i < MT; ++i)
    #pragma unroll
    for (int j = 0; j < 4; ++j) { acc[i][j][0]=0.f; acc[i][j][1]=0.f; acc[i][j][2]=0.f; acc[i][j][3]=0.f; }

  const int sr = l >> 2, sc = (l & 3) * 8;
  const u16* Ag = A + (size_t)(row0 + w * 32 + sr) * K + sc;
  u16* adst = a_s + w * 1024;
  const u16* Bg;
  u16* bdst;
  if (BN == 128) { Bg = B + (size_t)(col0 + w * 32 + sr) * K + sc; bdst = b_s + w * 1024; }
  else           { Bg = B + (size_t)(col0 + w * 16 + sr) * K + sc; bdst = b_s + w * 512; }

  for (int k0 = 0; k0 < K; k0 += 32) {
    __syncthreads();
    gload16(Ag + k0, adst);
    gload16(Ag + (size_t)16 * K + k0, adst + 512);
    gload16(Bg + k0, bdst);
    if (BN == 128) gload16(Bg + (size_t)16 * K + k0, bdst + 512);
    __syncthreads();
    short8 af[MT], bfr[4];
    #pragma unroll
    for (int mt = 0; mt < MT; ++mt) af[mt] = *(const short8*)&a_s[(wr + mt * 16 + lo) * 32 + g * 8];
    #pragma unroll
    for (int nt = 0; nt < 4; ++nt) bfr[nt] = *(const short8*)&b_s[(wc + nt * 16 + lo) * 32 + g * 8];
    #pragma unroll
    for (int mt = 0; mt < MT; ++mt)
      #pragma unroll
      for (int nt = 0; nt < 4; ++nt)
        acc[mt][nt] = MFMA16(af[mt], bfr[nt], acc[mt][nt]);
  }
  #pragma unroll
  for (int mt = 0; mt < MT; ++mt) {
    const int rrow = row0 + wr + mt * 16 + g * 4;
    #pragma unroll
    for (int nt = 0; nt < 4; ++nt) {
      const int ccol = col0 + wc + nt * 16 + lo;
      const float bv = BIAS ? bias[ccol] : 0.f;
      #pragma unroll
      for (int r = 0; r < 4; ++r) {
        const float v = acc[mt][nt][r] + bv;
        if (BF16OUT) ((u16*)Cv)[(size_t)(rrow + r) * N + ccol] = f2bf(v);
        else         ((float*)Cv)[(size_t)(rrow + r) * N + ccol] = v;
      }
    }
  }
}

// -------- fused in-place L2-normalize of 64-elem head segments (q & k) --------
__global__ __launch_bounds__(256) void norm_all(u16* __restrict__ qh, u16* __restrict__ kvp,
                                                const float* __restrict__ ls) {
  const int bid = blockIdx.x;
  const int t = threadIdx.x, h = t >> 4, ln = t & 15;
  u16* base; bool scale;
  if (bid < 2048) { base = qh + (size_t)bid * 1024; scale = true; }
  else            { base = kvp + (size_t)(bid - 2048) * 2048; scale = false; }
  u16* qp = base + h * 64 + ln * 4;
  ushort4 uv = *(const ushort4*)qp;
  float x0 = bf2f(uv.x), x1 = bf2f(uv.y), x2 = bf2f(uv.z), x3 = bf2f(uv.w);
  float ss = x0 * x0 + x1 * x1 + x2 * x2 + x3 * x3;
  ss += __shfl_xor(ss, 1); ss += __shfl_xor(ss, 2);
  ss += __shfl_xor(ss, 4); ss += __shfl_xor(ss, 8);
  float inv = 1.f / fmaxf(sqrtf(ss), 1e-12f);
  if (scale) inv *= __expf(fminf(ls[h], LOGIT_MAX));
  ushort4 ov;
  ov.x = f2bf(x0 * inv); ov.y = f2bf(x1 * inv);
  ov.z = f2bf(x2 * inv); ov.w = f2bf(x3 * inv);
  *(ushort4*)qp = ov;
}

// ---------------- Flash attention, bf16 MFMA, QBLK=64, KVBLK=64, 4 waves ----------------
// 2-phase pipeline: one __syncthreads per tile (drains gload_lds), prefetch of tile t+1
// issued before a raw lgkmcnt-only barrier so global loads stay in flight across compute.
__global__ __launch_bounds__(256) void attn_mfma(
    const u16* __restrict__ qn, const u16* __restrict__ kvp,
    const float* __restrict__ alibi, const u32* __restrict__ mbits,
    u16* __restrict__ xb)
{
  __shared__ __align__(16) u16 k_s[2][64 * 64];
  __shared__ __align__(16) u16 vT_s[2][64 * 64];
  __shared__ __align__(16) u16 p_s[4][16 * 64];
  const int t = threadIdx.x, w = t >> 6, l = t & 63, lo = l & 15, g = (l >> 4) & 3;
  const int bid = blockIdx.x;
  const int bh = bid & 31, b = bh >> 4, h = bh & 15;   // same-(b,h) blocks share an XCD
  const int n0 = (bid >> 5) * 64;

  const u16* qrow = qn + (size_t)(b * 1024 + n0 + w * 16 + lo) * 1024 + h * 64;
  const short8 qf0 = *(const short8*)(qrow + g * 8);
  const short8 qf1 = *(const short8*)(qrow + 32 + g * 8);

  const u16* kbase = kvp + (size_t)(b * 2048) * 2048 + h * 64;
  const u16* vbase = kbase + 1024;
  const float* albase = alibi + ((size_t)(bh * 1024 + n0 + w * 16 + lo)) * 2048;
  const u32* mb = mbits + b * 64;

  const int kr0 = w * 16 + (l >> 3);
  const int kcolb = (l & 7) * 16;
  const int vdq = (t & 7) * 8;        // d0 of this thread's V micro-tile
  const int vmp = (t >> 3) * 2;       // m (even) of this thread's V micro-tile

  float mrow = -1e30f, lrow = 0.f;
  f32x4 oa[4];
  #pragma unroll
  for (int d = 0; d < 4; ++d) { oa[d][0]=0.f; oa[d][1]=0.f; oa[d][2]=0.f; oa[d][3]=0.f; }

  // ---- prologue: stage tile 0 ----
  float4 al[4]; u32 w0m, w1m; short8 va, vb;
  {
    gload16((const char*)kbase + (size_t)kr0 * 4096 + (kcolb ^ SWZK(kr0)), (char*)k_s[0] + w * 2048);
    gload16((const char*)kbase + (size_t)(kr0 + 8) * 4096 + (kcolb ^ SWZK(kr0 + 8)), (char*)k_s[0] + w * 2048 + 1024);
    const u16* v0p = vbase + (size_t)vmp * 2048 + vdq;
    va = *(const short8*)v0p;
    vb = *(const short8*)(v0p + 2048);
    #pragma unroll
    for (int mt = 0; mt < 4; ++mt) al[mt] = *(const float4*)(albase + mt * 16 + g * 4);
    w0m = mb[0]; w1m = mb[1];
  }

  for (int ti = 0; ti < 32; ++ti) {
    const int cur = ti & 1;
    __syncthreads();   // vmcnt(0)+lgkmcnt(0) drain: K[ti] in k_s[cur] visible, va/vb/al/mask ready
    // write V[ti] (transposed+swizzled) to vT_s[cur]
    {
      char* vdst = (char*)vT_s[cur];
      #pragma unroll
      for (int j = 0; j < 8; ++j) {
        u32 pk = (u32)(u16)va[j] | ((u32)(u16)vb[j] << 16);
        int r = vdq + j;
        *(u32*)(vdst + r * 128 + ((vmp * 2) ^ SWZV(r))) = pk;
      }
    }
    // snapshot current tile's operands
    float4 cal[4];
    #pragma unroll
    for (int mt = 0; mt < 4; ++mt) cal[mt] = al[mt];
    const u32 cw0 = w0m, cw1 = w1m;
    // prefetch tile ti+1 (stays in flight across this tile's compute)
    if (ti < 31) {
      const int m1 = (ti + 1) * 64, nb = cur ^ 1;
      gload16((const char*)kbase + (size_t)(m1 + kr0) * 4096 + (kcolb ^ SWZK(kr0)), (char*)k_s[nb] + w * 2048);
      gload16((const char*)kbase + (size_t)(m1 + kr0 + 8) * 4096 + (kcolb ^ SWZK(kr0 + 8)), (char*)k_s[nb] + w * 2048 + 1024);
      const u16* v1p = vbase + (size_t)(m1 + vmp) * 2048 + vdq;
      va = *(const short8*)v1p;
      vb = *(const short8*)(v1p + 2048);
      #pragma unroll
      for (int mt = 0; mt < 4; ++mt) al[mt] = *(const float4*)(albase + m1 + mt * 16 + g * 4);
      w0m = mb[(m1 >> 5)]; w1m = mb[(m1 >> 5) + 1];
    }
    asm volatile("s_waitcnt lgkmcnt(0)" ::: "memory");  // V writes visible; vmcnt NOT drained
    __builtin_amdgcn_s_barrier();

    // ---- compute tile ti ----
    // QK^T (swapped): st[mt] holds S[n=lo][m = ti*64 + mt*16 + 4g + r]
    f32x4 st[4];
    #pragma unroll
    for (int mt = 0; mt < 4; ++mt) {
      const int r = mt * 16 + lo;
      const char* krow = (const char*)k_s[cur] + r * 128;
      short8 ka0 = *(const short8*)(krow + ((g * 16) ^ SWZK(r)));
      short8 ka1 = *(const short8*)(krow + ((64 + g * 16) ^ SWZK(r)));
      f32x4 z; z[0]=0.f; z[1]=0.f; z[2]=0.f; z[3]=0.f;
      st[mt] = MFMA16(ka0, qf0, z);
      st[mt] = MFMA16(ka1, qf1, st[mt]);
    }
    // alibi + padding mask (bitmask words, wave-uniform)
    float p[16];
    float pmax = -1e30f;
    #pragma unroll
    for (int mt = 0; mt < 4; ++mt) {
      const float aa[4] = {cal[mt].x, cal[mt].y, cal[mt].z, cal[mt].w};
      #pragma unroll
      for (int r = 0; r < 4; ++r) {
        const int idx = mt * 16 + g * 4 + r;
        const u32 wsel = (mt >= 2) ? cw1 : cw0;
        const float v = ((wsel >> (idx & 31)) & 1u) ? -1e30f : (st[mt][r] + aa[r]);
        p[mt * 4 + r] = v;
        pmax = fmaxf(pmax, v);
      }
    }
    pmax = fmaxf(pmax, __shfl_xor(pmax, 16));
    pmax = fmaxf(pmax, __shfl_xor(pmax, 32));
    const float mnew = fmaxf(mrow, pmax);
    const float f = __expf(mrow - mnew);
    float sum = 0.f;
    #pragma unroll
    for (int i = 0; i < 16; ++i) { p[i] = __expf(p[i] - mnew); sum += p[i]; }
    sum += __shfl_xor(sum, 16);
    sum += __shfl_xor(sum, 32);
    lrow = lrow * f + sum;
    mrow = mnew;
    // write P (bf16) to per-wave LDS, swizzled; read back as PV A-frags
    char* pwB = (char*)p_s[w];
    #pragma unroll
    for (int mt = 0; mt < 4; ++mt) {
      uint2 u;
      u.x = (u32)f2bf(p[mt * 4 + 0]) | ((u32)f2bf(p[mt * 4 + 1]) << 16);
      u.y = (u32)f2bf(p[mt * 4 + 2]) | ((u32)f2bf(p[mt * 4 + 3]) << 16);
      *(uint2*)(pwB + lo * 128 + ((mt * 32 + g * 8) ^ SWZK(lo))) = u;
    }
    asm volatile("" ::: "memory");  // order P write before P read (same wave, DS in-order)
    // rescale O accumulators (O row n = 4g+r; f lives at lane n)
    const float f0 = __shfl(f, 4 * g + 0), f1 = __shfl(f, 4 * g + 1);
    const float f2v = __shfl(f, 4 * g + 2), f3 = __shfl(f, 4 * g + 3);
    f32x4 fv; fv[0] = f0; fv[1] = f1; fv[2] = f2v; fv[3] = f3;
    #pragma unroll
    for (int d = 0; d < 4; ++d) oa[d] *= fv;
    // PV: O[n][dv] += P·V
    #pragma unroll
    for (int kt = 0; kt < 2; ++kt) {
      short8 pa = *(const short8*)(pwB + lo * 128 + ((kt * 64 + g * 16) ^ SWZK(lo)));
      #pragma unroll
      for (int d = 0; d < 4; ++d) {
        const int r = d * 16 + lo;
        short8 vf = *(const short8*)((const char*)vT_s[cur] + r * 128 + ((kt * 64 + g * 16) ^ SWZV(r)));
        oa[d] = MFMA16(pa, vf, oa[d]);
      }
    }
  }
  // epilogue: divide by row sums and store bf16
  const float l0 = __shfl(lrow, 4 * g + 0), l1 = __shfl(lrow, 4 * g + 1);
  const float l2 = __shfl(lrow, 4 * g + 2), l3 = __shfl(lrow, 4 * g + 3);
  const float iv[4] = {1.f / l0, 1.f / l1, 1.f / l2, 1.f / l3};
  u16* xrow = xb + (size_t)(b * 1024 + n0 + w * 16) * 1024 + h * 64;
  #pragma unroll
  for (int d = 0; d < 4; ++d)
    #pragma unroll
    for (int r = 0; r < 4; ++r)
      xrow[(size_t)(4 * g + r) * 1024 + d * 16 + lo] = f2bf(oa[d][r] * iv[r]);
}

extern "C" void kernel_launch(void* const* d_in, const int* in_sizes, int n_in,
                              void* d_out, int out_size, void* d_ws, size_t ws_size,
                              hipStream_t stream) {
  const float* q     = (const float*)d_in[0];   // [2,1024,1024]
  const float* kv    = (const float*)d_in[1];   // [2,2048,1024]
  const int*   pmask = (const int*)d_in[2];     // [2,2048] bool->int32
  const float* alibi = (const float*)d_in[3];   // [2,16,1024,2048]
  const float* Wq    = (const float*)d_in[4];   // [1024,1024]
  const float* Wkv   = (const float*)d_in[5];   // [2048,1024]
  const float* Wo    = (const float*)d_in[6];   // [1024,1024]
  const float* bo    = (const float*)d_in[7];   // [1024]
  const float* ls    = (const float*)d_in[8];   // [16]
  float* out = (float*)d_out;                   // [2,1024,1024]

  u16* ws = (u16*)d_ws;
  u16* q_bf   = ws;
  u16* kv_bf  = ws + (size_t)2  * 1024 * 1024;
  u16* Wq_bf  = ws + (size_t)6  * 1024 * 1024;
  u16* Wkv_bf = ws + (size_t)7  * 1024 * 1024;
  u16* Wo_bf  = ws + (size_t)9  * 1024 * 1024;
  u16* qh_bf  = ws + (size_t)10 * 1024 * 1024;  // [2048][1024]
  u16* kvp_bf = ws + (size_t)12 * 1024 * 1024;  // [4096][2048]
  u16* xb     = ws + (size_t)20 * 1024 * 1024;  // [2048][1024]
  u32* mbits  = (u32*)(ws + (size_t)22 * 1024 * 1024);  // [2][64]

  cast_all<<<5121, 256, 0, stream>>>(q, kv, Wq, Wkv, Wo, pmask,
                                     q_bf, kv_bf, Wq_bf, Wkv_bf, Wo_bf, mbits);

  gemm_bf16<64,  false, true><<<dim3(16, 16), 256, 0, stream>>>(q_bf,  Wq_bf,  nullptr, qh_bf,  2048, 1024, 1024);
  gemm_bf16<128, false, true><<<dim3(16, 32), 256, 0, stream>>>(kv_bf, Wkv_bf, nullptr, kvp_bf, 4096, 2048, 1024);

  norm_all<<<6144, 256, 0, stream>>>(qh_bf, kvp_bf, ls);

  attn_mfma<<<512, 256, 0, stream>>>(qh_bf, kvp_bf, alibi, mbits, xb);

  gemm_bf16<64, true, false><<<dim3(16, 16), 256, 0, stream>>>(xb, Wo_bf, bo, out, 2048, 1024, 1024);
}

// Round 5
// 177.388 us; speedup vs baseline: 6.8962x; 1.0004x over previous
//
#include <hip/hip_runtime.h>
#include <hip/hip_bf16.h>
#include <math.h>

typedef unsigned short u16;
typedef unsigned int u32;
using f32x4 = __attribute__((ext_vector_type(4))) float;
using short8 = __attribute__((ext_vector_type(8))) short;

#define LOGIT_MAX 4.605170185988091f
#define MFMA16(a,b,c) __builtin_amdgcn_mfma_f32_16x16x32_bf16((a),(b),(c),0,0,0)
// LDS XOR swizzles for 128B rows (m214: byte ^= ((row&7)<<4))
#define SWZK(r) ((((r)&7))<<4)
#define SWZV(r) (((((r)^((r)>>3))&7))<<4)
#define AT_SB __builtin_amdgcn_sched_barrier(0)

__device__ __forceinline__ u16 f2bf(float f) {
  u32 u = __float_as_uint(f);
  return (u16)((u + 0x7FFFu + ((u >> 16) & 1u)) >> 16);  // RNE
}
__device__ __forceinline__ float bf2f(u16 s) {
  return __uint_as_float(((u32)s) << 16);
}
__device__ __forceinline__ u32 cvt_pk_bf16(float a, float b) {  // low=bf16(a), high=bf16(b)
  u32 r;
  asm("v_cvt_pk_bf16_f32 %0, %1, %2" : "=v"(r) : "v"(a), "v"(b));
  return r;
}
__device__ __forceinline__ void gload16(const void* g, void* l) {
  __builtin_amdgcn_global_load_lds(
      (const __attribute__((address_space(1))) u32*)g,
      (__attribute__((address_space(3))) u32*)l, 16, 0, 0);
}

// ------- fused f32->bf16 casts (5 regions) + padding-mask->bitmask -------
__global__ __launch_bounds__(256) void cast_all(
    const float* __restrict__ q, const float* __restrict__ kv,
    const float* __restrict__ Wq, const float* __restrict__ Wkv,
    const float* __restrict__ Wo, const int* __restrict__ pm,
    u16* __restrict__ qb, u16* __restrict__ kvb, u16* __restrict__ wqb,
    u16* __restrict__ wkvb, u16* __restrict__ wob, u32* __restrict__ mbits) {
  const int bid = blockIdx.x, t = threadIdx.x;
  if (bid == 5120) {  // mask -> bits: [2][2048] int -> [2][64] u32
    if (t < 128) {
      u32 bits = 0;
      const int* mp = pm + (t >> 6) * 2048 + (t & 63) * 32;
      #pragma unroll
      for (int j = 0; j < 32; ++j) bits |= (mp[j] ? 1u : 0u) << j;
      mbits[t] = bits;
    }
    return;
  }
  const float* s; u16* d; int base;
  if (bid < 1024)      { s = q;   d = qb;   base = bid; }
  else if (bid < 3072) { s = kv;  d = kvb;  base = bid - 1024; }
  else if (bid < 3584) { s = Wq;  d = wqb;  base = bid - 3072; }
  else if (bid < 4608) { s = Wkv; d = wkvb; base = bid - 3584; }
  else                 { s = Wo;  d = wob;  base = bid - 4608; }
  const size_t i = ((size_t)base * 256 + t) * 8;
  float4 a = *(const float4*)(s + i);
  float4 b = *(const float4*)(s + i + 4);
  short8 v;
  v[0] = (short)f2bf(a.x); v[1] = (short)f2bf(a.y);
  v[2] = (short)f2bf(a.z); v[3] = (short)f2bf(a.w);
  v[4] = (short)f2bf(b.x); v[5] = (short)f2bf(b.y);
  v[6] = (short)f2bf(b.z); v[7] = (short)f2bf(b.w);
  *(short8*)(d + i) = v;
}

// ------------- GEMM NT bf16: C[M,N] = A[M,K] * B[N,K]^T -------------
// BN=128: 4 waves in 2x2, 64x64 each. BN=64: 4 waves stacked, 32x64 each.
// NORM: 0=none, 1=l2norm rows of 64-col head segs when col0<1024 (k), 2=l2norm+logit scale (q)
template<int BN, int NORM, bool BIAS, bool BF16OUT>
__global__ __launch_bounds__(256) void gemm_bf16(
    const u16* __restrict__ A, const u16* __restrict__ B,
    const float* __restrict__ bias, const float* __restrict__ ls,
    void* __restrict__ Cv, int M, int N, int K)
{
  constexpr int MT = (BN == 128) ? 4 : 2;
  __shared__ __align__(16) u16 a_s[128 * 32];
  __shared__ __align__(16) u16 b_s[BN * 32];
  const int t = threadIdx.x, w = t >> 6, l = t & 63, lo = l & 15, g = (l >> 4) & 3;
  const int row0 = blockIdx.y * 128, col0 = blockIdx.x * BN;
  const int wr = (BN == 128) ? ((w >> 1) * 64) : (w * 32);
  const int wc = (BN == 128) ? ((w & 1) * 64) : 0;
  f32x4 acc[MT][4];
  #pragma unroll
  for (int i = 0; i < MT; ++i)
    #pragma unroll
    for (int j = 0; j < 4; ++j) { acc[i][j][0]=0.f; acc[i][j][1]=0.f; acc[i][j][2]=0.f; acc[i][j][3]=0.f; }

  const int sr = l >> 2, sc = (l & 3) * 8;
  const u16* Ag = A + (size_t)(row0 + w * 32 + sr) * K + sc;
  u16* adst = a_s + w * 1024;
  const u16* Bg;
  u16* bdst;
  if (BN == 128) { Bg = B + (size_t)(col0 + w * 32 + sr) * K + sc; bdst = b_s + w * 1024; }
  else           { Bg = B + (size_t)(col0 + w * 16 + sr) * K + sc; bdst = b_s + w * 512; }

  for (int k0 = 0; k0 < K; k0 += 32) {
    __syncthreads();
    gload16(Ag + k0, adst);
    gload16(Ag + (size_t)16 * K + k0, adst + 512);
    gload16(Bg + k0, bdst);
    if (BN == 128) gload16(Bg + (size_t)16 * K + k0, bdst + 512);
    __syncthreads();
    short8 af[MT], bfr[4];
    #pragma unroll
    for (int mt = 0; mt < MT; ++mt) af[mt] = *(const short8*)&a_s[(wr + mt * 16 + lo) * 32 + g * 8];
    #pragma unroll
    for (int nt = 0; nt < 4; ++nt) bfr[nt] = *(const short8*)&b_s[(wc + nt * 16 + lo) * 32 + g * 8];
    #pragma unroll
    for (int mt = 0; mt < MT; ++mt)
      #pragma unroll
      for (int nt = 0; nt < 4; ++nt)
        acc[mt][nt] = MFMA16(af[mt], bfr[nt], acc[mt][nt]);
  }
  // fused L2-norm over each row's 64-col head segment (wave covers exactly 64 cols)
  if (NORM == 2 || (NORM == 1 && col0 < 1024)) {
    float scl = 1.f;
    if (NORM == 2) scl = __expf(fminf(ls[(col0 + wc) >> 6], LOGIT_MAX));
    #pragma unroll
    for (int mt = 0; mt < MT; ++mt)
      #pragma unroll
      for (int r = 0; r < 4; ++r) {
        float s = 0.f;
        #pragma unroll
        for (int nt = 0; nt < 4; ++nt) s = fmaf(acc[mt][nt][r], acc[mt][nt][r], s);
        s += __shfl_xor(s, 1); s += __shfl_xor(s, 2);
        s += __shfl_xor(s, 4); s += __shfl_xor(s, 8);
        float inv = scl / fmaxf(sqrtf(s), 1e-12f);
        #pragma unroll
        for (int nt = 0; nt < 4; ++nt) acc[mt][nt][r] *= inv;
      }
  }
  #pragma unroll
  for (int mt = 0; mt < MT; ++mt) {
    const int rrow = row0 + wr + mt * 16 + g * 4;
    #pragma unroll
    for (int nt = 0; nt < 4; ++nt) {
      const int ccol = col0 + wc + nt * 16 + lo;
      const float bv = BIAS ? bias[ccol] : 0.f;
      #pragma unroll
      for (int r = 0; r < 4; ++r) {
        const float v = acc[mt][nt][r] + bv;
        if (BF16OUT) ((u16*)Cv)[(size_t)(rrow + r) * N + ccol] = f2bf(v);
        else         ((float*)Cv)[(size_t)(rrow + r) * N + ccol] = v;
      }
    }
  }
}

// ---------------- Flash attention, bf16 MFMA, QBLK=64, KVBLK=64, 4 waves ----------------
// Counted-vmcnt pipeline: raw s_barriers, no vmcnt(0) drain in loop.
// Per body: [vmcnt(6) | V ds_write | issue K/V(t+1) | lgkmcnt(0)+barrier | compute(t) | issue al(t+2) | barrier]
__global__ __launch_bounds__(256) void attn_mfma(
    const u16* __restrict__ qn, const u16* __restrict__ kvp,
    const float* __restrict__ alibi, const u32* __restrict__ mbits,
    u16* __restrict__ xb)
{
  __shared__ __align__(16) u16 k_s[2][64 * 64];
  __shared__ __align__(16) u16 vT_s[2][64 * 64];
  __shared__ __align__(16) u16 p_s[4][16 * 64];
  const int t = threadIdx.x, w = t >> 6, l = t & 63, lo = l & 15, g = (l >> 4) & 3;
  const int bid = blockIdx.x;
  const int bh = bid & 31, b = bh >> 4, h = bh & 15;   // same-(b,h) blocks share an XCD
  const int n0 = (bid >> 5) * 64;

  const u16* qrow = qn + (size_t)(b * 1024 + n0 + w * 16 + lo) * 1024 + h * 64;
  const short8 qf0 = *(const short8*)(qrow + g * 8);
  const short8 qf1 = *(const short8*)(qrow + 32 + g * 8);

  const u16* kbase = kvp + (size_t)(b * 2048) * 2048 + h * 64;
  const u16* vbase = kbase + 1024;
  const float* albase = alibi + ((size_t)(bh * 1024 + n0 + w * 16 + lo)) * 2048;

  const int kr0 = w * 16 + (l >> 3);
  const int kcolb = (l & 7) * 16;
  const int vdq = (t & 7) * 8;        // d0 of this thread's V micro-tile
  const int vmp = (t >> 3) * 2;       // m (even) of this thread's V micro-tile

  float mrow = -1e30f, lrow = 0.f;
  f32x4 oa[4];
  #pragma unroll
  for (int d = 0; d < 4; ++d) { oa[d][0]=0.f; oa[d][1]=0.f; oa[d][2]=0.f; oa[d][3]=0.f; }

  // ---- prologue: mask word, al(0)->A, K(0), V(0)->A, al(1)->B ----
  const u32 mword = mbits[b * 64 + l];
  AT_SB;
  float4 alA[4], alB[4];
  short8 vaA, vbA, vaB, vbB;
  #pragma unroll
  for (int mt = 0; mt < 4; ++mt) alA[mt] = *(const float4*)(albase + mt * 16 + g * 4);
  AT_SB;
  gload16((const char*)kbase + (size_t)kr0 * 4096 + (kcolb ^ SWZK(kr0)), (char*)k_s[0] + w * 2048);
  gload16((const char*)kbase + (size_t)(kr0 + 8) * 4096 + (kcolb ^ SWZK(kr0 + 8)), (char*)k_s[0] + w * 2048 + 1024);
  AT_SB;
  {
    const u16* v0p = vbase + (size_t)vmp * 2048 + vdq;
    vaA = *(const short8*)v0p;
    vbA = *(const short8*)(v0p + 2048);
  }
  AT_SB;
  #pragma unroll
  for (int mt = 0; mt < 4; ++mt) alB[mt] = *(const float4*)(albase + 64 + mt * 16 + g * 4);
  AT_SB;

#define COMPUTE(TI, CUR, AL) {                                                      \
    f32x4 st[4];                                                                    \
    _Pragma("unroll")                                                               \
    for (int mt = 0; mt < 4; ++mt) {                                                \
      const int r = mt * 16 + lo;                                                   \
      const char* krow = (const char*)k_s[CUR] + r * 128;                           \
      short8 ka0 = *(const short8*)(krow + ((g * 16) ^ SWZK(r)));                   \
      short8 ka1 = *(const short8*)(krow + ((64 + g * 16) ^ SWZK(r)));              \
      f32x4 z; z[0]=0.f; z[1]=0.f; z[2]=0.f; z[3]=0.f;                              \
      st[mt] = MFMA16(ka0, qf0, z);                                                 \
      st[mt] = MFMA16(ka1, qf1, st[mt]);                                            \
    }                                                                               \
    const u32 cw0 = __shfl(mword, (TI) * 2), cw1 = __shfl(mword, (TI) * 2 + 1);     \
    float p[16]; float pmax = -1e30f;                                               \
    _Pragma("unroll")                                                               \
    for (int mt = 0; mt < 4; ++mt) {                                                \
      const float aa[4] = {AL[mt].x, AL[mt].y, AL[mt].z, AL[mt].w};                 \
      const u32 wsel = (mt >= 2) ? cw1 : cw0;                                       \
      _Pragma("unroll")                                                             \
      for (int r = 0; r < 4; ++r) {                                                 \
        const int idx = mt * 16 + g * 4 + r;                                        \
        const float v = ((wsel >> (idx & 31)) & 1u) ? -1e30f : (st[mt][r] + aa[r]); \
        p[mt * 4 + r] = v;                                                          \
        pmax = fmaxf(pmax, v);                                                      \
      }                                                                             \
    }                                                                               \
    pmax = fmaxf(pmax, __shfl_xor(pmax, 16));                                       \
    pmax = fmaxf(pmax, __shfl_xor(pmax, 32));                                       \
    const float mnew = fmaxf(mrow, pmax);                                           \
    const float f = __expf(mrow - mnew);                                            \
    float sum = 0.f;                                                                \
    _Pragma("unroll")                                                               \
    for (int i = 0; i < 16; ++i) { p[i] = __expf(p[i] - mnew); sum += p[i]; }       \
    sum += __shfl_xor(sum, 16);                                                     \
    sum += __shfl_xor(sum, 32);                                                     \
    lrow = lrow * f + sum;                                                          \
    mrow = mnew;                                                                    \
    char* pwB = (char*)p_s[w];                                                      \
    _Pragma("unroll")                                                               \
    for (int mt = 0; mt < 4; ++mt) {                                                \
      uint2 u;                                                                      \
      u.x = cvt_pk_bf16(p[mt * 4 + 0], p[mt * 4 + 1]);                              \
      u.y = cvt_pk_bf16(p[mt * 4 + 2], p[mt * 4 + 3]);                              \
      *(uint2*)(pwB + lo * 128 + ((mt * 32 + g * 8) ^ SWZK(lo))) = u;               \
    }                                                                               \
    asm volatile("" ::: "memory");                                                  \
    const float f0 = __shfl(f, 4 * g + 0), f1 = __shfl(f, 4 * g + 1);               \
    const float f2v = __shfl(f, 4 * g + 2), f3 = __shfl(f, 4 * g + 3);              \
    f32x4 fv; fv[0] = f0; fv[1] = f1; fv[2] = f2v; fv[3] = f3;                      \
    _Pragma("unroll")                                                               \
    for (int d = 0; d < 4; ++d) oa[d] *= fv;                                        \
    _Pragma("unroll")                                                               \
    for (int kt = 0; kt < 2; ++kt) {                                                \
      short8 pa = *(const short8*)(pwB + lo * 128 + ((kt * 64 + g * 16) ^ SWZK(lo))); \
      _Pragma("unroll")                                                             \
      for (int d = 0; d < 4; ++d) {                                                 \
        const int r = d * 16 + lo;                                                  \
        short8 vf = *(const short8*)((const char*)vT_s[CUR] + r * 128 + ((kt * 64 + g * 16) ^ SWZV(r))); \
        oa[d] = MFMA16(pa, vf, oa[d]);                                              \
      }                                                                             \
    }                                                                               \
  }

#define BODY(TI, CUR, Vca, Vcb, Vna, Vnb, ALc, WLIT) {                              \
    asm volatile("s_waitcnt vmcnt(" WLIT ")" ::: "memory"); AT_SB;                  \
    { char* vdst = (char*)vT_s[CUR];                                                \
      _Pragma("unroll")                                                             \
      for (int j = 0; j < 8; ++j) {                                                 \
        u32 pk = (u32)(u16)Vca[j] | ((u32)(u16)Vcb[j] << 16);                       \
        int r = vdq + j;                                                            \
        *(u32*)(vdst + r * 128 + ((vmp * 2) ^ SWZV(r))) = pk; } }                   \
    AT_SB;                                                                          \
    if ((TI) < 31) {                                                                \
      const int m1 = ((TI) + 1) * 64;                                               \
      gload16((const char*)kbase + (size_t)(m1 + kr0) * 4096 + (kcolb ^ SWZK(kr0)), \
              (char*)k_s[(CUR) ^ 1] + w * 2048);                                    \
      gload16((const char*)kbase + (size_t)(m1 + kr0 + 8) * 4096 + (kcolb ^ SWZK(kr0 + 8)), \
              (char*)k_s[(CUR) ^ 1] + w * 2048 + 1024);                             \
      AT_SB;                                                                        \
      const u16* v1p = vbase + (size_t)(m1 + vmp) * 2048 + vdq;                     \
      Vna = *(const short8*)v1p;                                                    \
      Vnb = *(const short8*)(v1p + 2048);                                           \
    }                                                                               \
    AT_SB;                                                                          \
    asm volatile("s_waitcnt lgkmcnt(0)" ::: "memory");                              \
    __builtin_amdgcn_s_barrier(); AT_SB;                                            \
    COMPUTE(TI, CUR, ALc);                                                          \
    AT_SB;                                                                          \
    if ((TI) < 30) {                                                                \
      const int m2 = ((TI) + 2) * 64;                                               \
      _Pragma("unroll")                                                             \
      for (int mt = 0; mt < 4; ++mt)                                                \
        ALc[mt] = *(const float4*)(albase + m2 + mt * 16 + g * 4);                  \
    }                                                                               \
    AT_SB;                                                                          \
    __builtin_amdgcn_s_barrier();                                                   \
  }

  for (int t2 = 0; t2 < 30; t2 += 2) {
    BODY(t2,     0, vaA, vbA, vaB, vbB, alA, "6");
    BODY(t2 + 1, 1, vaB, vbB, vaA, vbA, alB, "6");
  }
  BODY(30, 0, vaA, vbA, vaB, vbB, alA, "6");
  BODY(31, 1, vaB, vbB, vaA, vbA, alB, "2");
#undef BODY
#undef COMPUTE

  // epilogue: divide by row sums and store bf16
  const float l0 = __shfl(lrow, 4 * g + 0), l1 = __shfl(lrow, 4 * g + 1);
  const float l2 = __shfl(lrow, 4 * g + 2), l3 = __shfl(lrow, 4 * g + 3);
  const float iv[4] = {1.f / l0, 1.f / l1, 1.f / l2, 1.f / l3};
  u16* xrow = xb + (size_t)(b * 1024 + n0 + w * 16) * 1024 + h * 64;
  #pragma unroll
  for (int d = 0; d < 4; ++d)
    #pragma unroll
    for (int r = 0; r < 4; ++r)
      xrow[(size_t)(4 * g + r) * 1024 + d * 16 + lo] = f2bf(oa[d][r] * iv[r]);
}

extern "C" void kernel_launch(void* const* d_in, const int* in_sizes, int n_in,
                              void* d_out, int out_size, void* d_ws, size_t ws_size,
                              hipStream_t stream) {
  const float* q     = (const float*)d_in[0];   // [2,1024,1024]
  const float* kv    = (const float*)d_in[1];   // [2,2048,1024]
  const int*   pmask = (const int*)d_in[2];     // [2,2048] bool->int32
  const float* alibi = (const float*)d_in[3];   // [2,16,1024,2048]
  const float* Wq    = (const float*)d_in[4];   // [1024,1024]
  const float* Wkv   = (const float*)d_in[5];   // [2048,1024]
  const float* Wo    = (const float*)d_in[6];   // [1024,1024]
  const float* bo    = (const float*)d_in[7];   // [1024]
  const float* ls    = (const float*)d_in[8];   // [16]
  float* out = (float*)d_out;                   // [2,1024,1024]

  u16* ws = (u16*)d_ws;
  u16* q_bf   = ws;
  u16* kv_bf  = ws + (size_t)2  * 1024 * 1024;
  u16* Wq_bf  = ws + (size_t)6  * 1024 * 1024;
  u16* Wkv_bf = ws + (size_t)7  * 1024 * 1024;
  u16* Wo_bf  = ws + (size_t)9  * 1024 * 1024;
  u16* qh_bf  = ws + (size_t)10 * 1024 * 1024;  // [2048][1024] normalized*scale
  u16* kvp_bf = ws + (size_t)12 * 1024 * 1024;  // [4096][2048] k normalized | v
  u16* xb     = ws + (size_t)20 * 1024 * 1024;  // [2048][1024]
  u32* mbits  = (u32*)(ws + (size_t)22 * 1024 * 1024);  // [2][64]

  cast_all<<<5121, 256, 0, stream>>>(q, kv, Wq, Wkv, Wo, pmask,
                                     q_bf, kv_bf, Wq_bf, Wkv_bf, Wo_bf, mbits);

  gemm_bf16<64, 2, false, true><<<dim3(16, 16), 256, 0, stream>>>(q_bf,  Wq_bf,  nullptr, ls, qh_bf,  2048, 1024, 1024);
  gemm_bf16<128, 1, false, true><<<dim3(16, 32), 256, 0, stream>>>(kv_bf, Wkv_bf, nullptr, nullptr, kvp_bf, 4096, 2048, 1024);

  attn_mfma<<<512, 256, 0, stream>>>(qh_bf, kvp_bf, alibi, mbits, xb);

  gemm_bf16<64, 0, true, false><<<dim3(16, 16), 256, 0, stream>>>(xb, Wo_bf, bo, nullptr, out, 2048, 1024, 1024);
}